// Round 12
// baseline (2968.026 us; speedup 1.0000x reference)
//
#include <hip/hip_runtime.h>
#include <math.h>

// VisionMamba forward. Round 23: scan pass loops made compile-time-trip —
// uniform unrolled base tb=48c+4 for all chunks + peeled t=0..3 group for
// c==0. ds_read addresses become base+immediate (kills per-iter address
// math + loop control, lets compiler batch LDS reads). conv_silu widened
// to 8 e's/thread (16B ushort8 loads, identical fmaf order).
// Rest identical to R22 (2888 µs; scan 67 µs, VALUBusy 88%).
// B=64, L=196, D_MODEL=192, D_INNER=384, D_STATE=16, DT_RANK=12, DEPTH=24.

#define DEPTH 24
#define DM 192
#define DI 384
#define DS 16
#define DR 12
#define SEQL 196
#define BATCH 64
#define MROWS (BATCH*SEQL)   // 12544
#define XDP 8624             // x_dbl_t per-b plane: 44*196 floats
#define LOG2E 1.44269504088896340736f

typedef unsigned short ushort_t;
typedef __bf16 bf16x8 __attribute__((ext_vector_type(8)));
typedef float f32x4 __attribute__((ext_vector_type(4)));
typedef ushort_t ush8 __attribute__((ext_vector_type(8)));

__device__ __forceinline__ float sigmoidf_(float x) { return 1.f / (1.f + __expf(-x)); }

__device__ __forceinline__ ushort_t f2bf(float f) {  // RNE fp32->bf16
    union { float f; unsigned u; } c; c.f = f;
    unsigned u = c.u;
    return (ushort_t)((u + 0x7FFFu + ((u >> 16) & 1u)) >> 16);
}
__device__ __forceinline__ float bf2f(ushort_t u) {
    union { unsigned u; float f; } c; c.u = ((unsigned)u) << 16;
    return c.f;
}

__device__ __forceinline__ void load_lds16(const ushort_t* g, ushort_t* l) {
    __builtin_amdgcn_global_load_lds((__attribute__((address_space(1))) void*)g,
                                     (__attribute__((address_space(3))) void*)l, 16, 0, 0);
}

// DPP move: result = src permuted by CTRL; all perms used stay within valid
// lanes so `oldv` is never observed. Pure VALU, no LDS pipe.
template<int CTRL>
__device__ __forceinline__ float dpp_mov(float oldv, float src) {
    return __builtin_bit_cast(float, __builtin_amdgcn_update_dpp(
        __builtin_bit_cast(int, oldv), __builtin_bit_cast(int, src),
        CTRL, 0xF, 0xF, false));
}

// Butterfly sum over the 16 lanes of a DPP row: xor1, xor2, xor7, xor15
// generate the full 16-group; every lane ends with the row sum.
__device__ __forceinline__ float row16_sum(float v) {
    v += dpp_mov<0xB1>(0.f, v);   // quad_perm [1,0,3,2]  (xor 1)
    v += dpp_mov<0x4E>(0.f, v);   // quad_perm [2,3,0,1]  (xor 2)
    v += dpp_mov<0x141>(0.f, v);  // row_half_mirror      (xor 7)
    v += dpp_mov<0x140>(0.f, v);  // row_mirror           (xor 15)
    return v;
}

// ---------------- fp32 -> bf16 bulk convert, 4 elems/thread ----------------
__global__ void f2bf4_kernel(const float* __restrict__ src, ushort_t* __restrict__ dst, int n4) {
    int i = blockIdx.x * 256 + threadIdx.x;
    if (i >= n4) return;
    float4 v = ((const float4*)src)[i];
    union { ushort_t s[4]; uint2 u; } o;
    o.s[0] = f2bf(v.x); o.s[1] = f2bf(v.y); o.s[2] = f2bf(v.z); o.s[3] = f2bf(v.w);
    ((uint2*)dst)[i] = o.u;
}

// xp_w [24][44][384] -> padded bf16 [24][64][384], rows 44..63 = 0
__global__ void xp_pad_kernel(const float* __restrict__ src, ushort_t* __restrict__ dst) {
    int i = blockIdx.x * 256 + threadIdx.x;
    if (i >= DEPTH * 64 * 384) return;
    int col = i % 384, row = (i / 384) & 63, d = i / (384 * 64);
    float v = (row < 44) ? src[(size_t)d * 44 * 384 + row * 384 + col] : 0.f;
    dst[i] = f2bf(v);
}

// ---------------- out = LayerNorm(residual)  (no accumulation) ----------------
template<bool BF>
__global__ void ln_kernel(const float* __restrict__ residual,
                          const float* __restrict__ w, const float* __restrict__ b,
                          void* __restrict__ out_) {
    int wave = threadIdx.x >> 6, lane = threadIdx.x & 63;
    int row = blockIdx.x * 4 + wave;
    const float* rr = residual + (size_t)row * DM;
    float v0 = rr[lane];
    float v1 = rr[lane + 64];
    float v2 = rr[lane + 128];
    float s = v0 + v1 + v2;
    #pragma unroll
    for (int off = 32; off > 0; off >>= 1) s += __shfl_down(s, off);
    float mean = __shfl(s, 0) * (1.f / DM);
    float d0 = v0 - mean, d1 = v1 - mean, d2 = v2 - mean;
    float q = d0 * d0 + d1 * d1 + d2 * d2;
    #pragma unroll
    for (int off = 32; off > 0; off >>= 1) q += __shfl_down(q, off);
    float rstd = rsqrtf(__shfl(q, 0) * (1.f / DM) + 1e-5f);
    float o0 = d0 * rstd * w[lane]       + b[lane];
    float o1 = d1 * rstd * w[lane + 64]  + b[lane + 64];
    float o2 = d2 * rstd * w[lane + 128] + b[lane + 128];
    if constexpr (BF) {
        ushort_t* o = (ushort_t*)out_ + (size_t)row * DM;
        o[lane] = f2bf(o0); o[lane + 64] = f2bf(o1); o[lane + 128] = f2bf(o2);
    } else {
        float* o = (float*)out_ + (size_t)row * DM;
        o[lane] = o0; o[lane + 64] = o1; o[lane + 128] = o2;
    }
}

// ---------------- bf16 MFMA GEMM: C = A[M,K]bf16 * W[N,K]bf16^T ----------------
// BM parametrized. RESADD: C += result (fp32). OBF: write bf16 output.
template<int BM, int BN, int WM, int WN, int NST, bool TC, bool RESADD, bool OBF>
__global__ __launch_bounds__(256, 2) void gemm_mfma(const ushort_t* __restrict__ A,
        const ushort_t* __restrict__ W, void* __restrict__ C, int K, int ldC) {
    constexpr int FM = BM / (WM * 16);
    constexpr int FN = BN / (WN * 16);
    __shared__ ushort_t sA[BM * 32];
    __shared__ ushort_t sB[BN * 32];
    const int t = threadIdx.x;
    const int wave = t >> 6, lane = t & 63;
    const int lr = lane & 15, lq = lane >> 4;
    const int wr = wave / WN, wc = wave % WN;
    const int m0 = blockIdx.x * BM, n0 = blockIdx.y * BN;
    const int wbase = t & ~63;

    f32x4 acc[FM][FN];
    #pragma unroll
    for (int i = 0; i < FM; i++)
        #pragma unroll
        for (int j = 0; j < FN; j++) acc[i][j] = f32x4{0.f, 0.f, 0.f, 0.f};

    for (int k0 = 0; k0 < K; k0 += 32) {
        __syncthreads();
        #pragma unroll
        for (int c = 0; c < BM * 4 / 256; c++) { // A: BM*4 slots
            int s = c * 256 + t;
            int row = s >> 2;
            int quad = (s & 3) ^ ((row >> 1) & 3);
            load_lds16(A + (size_t)(m0 + row) * K + k0 + quad * 8,
                       sA + (size_t)(c * 256 + wbase) * 8);
        }
        #pragma unroll
        for (int c = 0; c < BN * 4 / 256; c++) { // B: BN*4 slots
            int s = c * 256 + t;
            int row = s >> 2;
            int quad = (s & 3) ^ ((row >> 1) & 3);
            load_lds16(W + (size_t)(n0 + row) * K + k0 + quad * 8,
                       sB + (size_t)(c * 256 + wbase) * 8);
        }
        __syncthreads();
        bf16x8 af[FM], bfr[FN];
        #pragma unroll
        for (int i = 0; i < FM; i++) {
            int row = wr * FM * 16 + i * 16 + lr;
            int slot = (row << 2) | (lq ^ ((row >> 1) & 3));
            af[i] = *(const bf16x8*)&sA[(size_t)slot * 8];
        }
        #pragma unroll
        for (int j = 0; j < FN; j++) {
            int row = wc * FN * 16 + j * 16 + lr;
            int slot = (row << 2) | (lq ^ ((row >> 1) & 3));
            bfr[j] = *(const bf16x8*)&sB[(size_t)slot * 8];
        }
        #pragma unroll
        for (int i = 0; i < FM; i++)
            #pragma unroll
            for (int j = 0; j < FN; j++)
                acc[i][j] = __builtin_amdgcn_mfma_f32_16x16x32_bf16(af[i], bfr[j], acc[i][j], 0, 0, 0);
    }
    // C/D layout: col = lane&15, row = (lane>>4)*4 + reg
    int crow0 = m0 + wr * FM * 16 + lq * 4;
    int ccol0 = n0 + wc * FN * 16 + lr;
    if constexpr (TC) {
        #pragma unroll
        for (int i = 0; i < FM; i++) {
            int m = crow0 + i * 16;
            int bb = m / 196, l = m % 196;
            #pragma unroll
            for (int j = 0; j < FN; j++) {
                int col = ccol0 + j * 16;
                if (col < 44) {
                    float4 v = {acc[i][j][0], acc[i][j][1], acc[i][j][2], acc[i][j][3]};
                    *(float4*)((float*)C + (size_t)bb * XDP + (size_t)col * 196 + l) = v;
                }
            }
        }
    } else {
        #pragma unroll
        for (int i = 0; i < FM; i++)
            #pragma unroll
            for (int j = 0; j < FN; j++) {
                if (wc * FN + j >= NST) continue;
                if constexpr (OBF) {
                    ushort_t* cp = (ushort_t*)C + (size_t)(crow0 + i * 16) * ldC + ccol0 + j * 16;
                    #pragma unroll
                    for (int r = 0; r < 4; r++) cp[(size_t)r * ldC] = f2bf(acc[i][j][r]);
                } else {
                    float* cp = (float*)C + (size_t)(crow0 + i * 16) * ldC + ccol0 + j * 16;
                    #pragma unroll
                    for (int r = 0; r < 4; r++) {
                        if constexpr (RESADD) cp[(size_t)r * ldC] += acc[i][j][r];
                        else                  cp[(size_t)r * ldC]  = acc[i][j][r];
                    }
                }
            }
    }
}

// ---------------- Patch-embed bf16 MFMA with im2col A-loader ----------------
// Writes the residual buffer directly (bias included) — replaces memset+add.
__global__ __launch_bounds__(256, 2) void gemm_patch_mfma(const ushort_t* __restrict__ Xbf,
        const ushort_t* __restrict__ Wbf, const float* __restrict__ bias, float* __restrict__ C) {
    constexpr int FM = 2, FN = 4;
    __shared__ ushort_t sA[128 * 32];
    __shared__ ushort_t sB[64 * 32];
    const int t = threadIdx.x;
    const int wave = t >> 6, lane = t & 63;
    const int lr = lane & 15, lq = lane >> 4;
    const int m0 = blockIdx.x * 128, n0 = blockIdx.y * 64;
    const int wbase = t & ~63;

    const ushort_t* abase[2];
    int aquad[2];
    #pragma unroll
    for (int c = 0; c < 2; c++) {
        int s = c * 256 + t;
        int row = s >> 2;
        aquad[c] = (s & 3) ^ ((row >> 1) & 3);
        int m = m0 + row;
        int b = m / 196, r = m % 196, py = r / 14, px = r % 14;
        abase[c] = Xbf + (size_t)b * 150528 + py * 3584 + px * 16;
    }
    int brow = t >> 2;
    int bquad = (t & 3) ^ ((brow >> 1) & 3);
    const ushort_t* bbase = Wbf + (size_t)(n0 + brow) * 768 + bquad * 8;

    f32x4 acc[FM][FN];
    #pragma unroll
    for (int i = 0; i < FM; i++)
        #pragma unroll
        for (int j = 0; j < FN; j++) acc[i][j] = f32x4{0.f, 0.f, 0.f, 0.f};

    for (int k0 = 0; k0 < 768; k0 += 32) {
        __syncthreads();
        #pragma unroll
        for (int c = 0; c < 2; c++) {
            int k = k0 + aquad[c] * 8;
            int ci = k >> 8, ky = (k >> 4) & 15, kx0 = k & 15;
            load_lds16(abase[c] + ci * 50176 + ky * 224 + kx0,
                       sA + (size_t)(c * 256 + wbase) * 8);
        }
        load_lds16(bbase + k0, sB + (size_t)wbase * 8);
        __syncthreads();
        bf16x8 af[FM], bfr[FN];
        #pragma unroll
        for (int i = 0; i < FM; i++) {
            int row = wave * FM * 16 + i * 16 + lr;
            int slot = (row << 2) | (lq ^ ((row >> 1) & 3));
            af[i] = *(const bf16x8*)&sA[(size_t)slot * 8];
        }
        #pragma unroll
        for (int j = 0; j < FN; j++) {
            int row = j * 16 + lr;
            int slot = (row << 2) | (lq ^ ((row >> 1) & 3));
            bfr[j] = *(const bf16x8*)&sB[(size_t)slot * 8];
        }
        #pragma unroll
        for (int i = 0; i < FM; i++)
            #pragma unroll
            for (int j = 0; j < FN; j++)
                acc[i][j] = __builtin_amdgcn_mfma_f32_16x16x32_bf16(af[i], bfr[j], acc[i][j], 0, 0, 0);
    }
    int crow0 = m0 + wave * FM * 16 + lq * 4;
    int ccol0 = n0 + lr;
    #pragma unroll
    for (int i = 0; i < FM; i++)
        #pragma unroll
        for (int j = 0; j < FN; j++) {
            int col = ccol0 + j * 16;
            float bv = bias[col];
            float* cp = C + (size_t)(crow0 + i * 16) * DM + col;
            #pragma unroll
            for (int r = 0; r < 4; r++) cp[(size_t)r * DM] = acc[i][j][r] + bv;
        }
}

// ---------------- Small fp32 GEMM (head only) ----------------
template<bool BIAS>
__global__ __launch_bounds__(256, 2) void gemm64(const float* __restrict__ A,
        const float* __restrict__ W, const float* __restrict__ bias,
        float* __restrict__ C, int M, int N, int K) {
    __shared__ float As[32][68];
    __shared__ float Ws[32][68];
    int t = threadIdx.x;
    int m0 = blockIdx.x * 64, n0 = blockIdx.y * 64;
    int lr = t >> 2, lk = (t & 3) * 4;
    int am = m0 + lr; bool avld = am < M;
    const float* Ap = A + (size_t)(avld ? am : 0) * K + lk;
    int wn = n0 + lr; bool wv = wn < N;
    const float* Wp = W + (size_t)(wv ? wn : 0) * K + lk;
    int tm = (t >> 4) * 4, tn = (t & 15) * 4;
    float acc[4][4];
    #pragma unroll
    for (int i = 0; i < 4; i++)
        #pragma unroll
        for (int j = 0; j < 4; j++) acc[i][j] = 0.f;

    for (int k0 = 0; k0 < K; k0 += 32) {
        float4 a0 = make_float4(0.f, 0.f, 0.f, 0.f), a1 = a0, w0 = a0, w1 = a0;
        if (avld) { a0 = *(const float4*)(Ap + k0); a1 = *(const float4*)(Ap + k0 + 16); }
        if (wv)   { w0 = *(const float4*)(Wp + k0); w1 = *(const float4*)(Wp + k0 + 16); }
        __syncthreads();
        As[lk + 0][lr] = a0.x; As[lk + 1][lr] = a0.y; As[lk + 2][lr] = a0.z; As[lk + 3][lr] = a0.w;
        As[lk + 16][lr] = a1.x; As[lk + 17][lr] = a1.y; As[lk + 18][lr] = a1.z; As[lk + 19][lr] = a1.w;
        Ws[lk + 0][lr] = w0.x; Ws[lk + 1][lr] = w0.y; Ws[lk + 2][lr] = w0.z; Ws[lk + 3][lr] = w0.w;
        Ws[lk + 16][lr] = w1.x; Ws[lk + 17][lr] = w1.y; Ws[lk + 18][lr] = w1.z; Ws[lk + 19][lr] = w1.w;
        __syncthreads();
        #pragma unroll
        for (int kk = 0; kk < 32; kk++) {
            float4 x0 = *(const float4*)&As[kk][tm];
            float4 y0 = *(const float4*)&Ws[kk][tn];
            float av[4] = {x0.x, x0.y, x0.z, x0.w};
            float bv[4] = {y0.x, y0.y, y0.z, y0.w};
            #pragma unroll
            for (int i = 0; i < 4; i++)
                #pragma unroll
                for (int j = 0; j < 4; j++) acc[i][j] = fmaf(av[i], bv[j], acc[i][j]);
        }
    }
    #pragma unroll
    for (int i = 0; i < 4; i++) {
        int m = m0 + tm + i;
        if (m >= M) continue;
        float* cr = C + (size_t)m * N;
        int n = n0 + tn;
        if (n < N) {
            float4 v = {acc[i][0], acc[i][1], acc[i][2], acc[i][3]};
            if (BIAS) { v.x += bias[n]; v.y += bias[n + 1]; v.z += bias[n + 2]; v.w += bias[n + 3]; }
            *(float4*)(cr + n) = v;
        }
    }
}

// ------------- depthwise causal conv(4) + SiLU (bf16 in) -> bf16, 8 e's/thread ----
__global__ void conv_silu_kernel(const ushort_t* __restrict__ xz, const float* __restrict__ cw,
                                 const float* __restrict__ cb, ushort_t* __restrict__ xcbf) {
    int idx = blockIdx.x * 256 + threadIdx.x;
    if (idx >= MROWS * (DI / 8)) return;
    int eq = idx % (DI / 8); int bl = idx / (DI / 8);
    int l = bl % SEQL; int b = bl / SEQL;
    int e8 = eq * 8;
    const ushort_t* base = xz + (size_t)(b * SEQL) * 768 + e8;
    float4 w[8];
    #pragma unroll
    for (int k = 0; k < 8; k++) w[k] = *(const float4*)(cw + (e8 + k) * 4);
    float acc[8];
    {
        float4 b0 = *(const float4*)(cb + e8);
        float4 b1 = *(const float4*)(cb + e8 + 4);
        acc[0] = b0.x; acc[1] = b0.y; acc[2] = b0.z; acc[3] = b0.w;
        acc[4] = b1.x; acc[5] = b1.y; acc[6] = b1.z; acc[7] = b1.w;
    }
    if (l >= 3) { ush8 xq = *(const ush8*)(base + (size_t)(l - 3) * 768);
        #pragma unroll
        for (int k = 0; k < 8; k++) acc[k] = fmaf(bf2f(xq[k]), w[k].x, acc[k]); }
    if (l >= 2) { ush8 xq = *(const ush8*)(base + (size_t)(l - 2) * 768);
        #pragma unroll
        for (int k = 0; k < 8; k++) acc[k] = fmaf(bf2f(xq[k]), w[k].y, acc[k]); }
    if (l >= 1) { ush8 xq = *(const ush8*)(base + (size_t)(l - 1) * 768);
        #pragma unroll
        for (int k = 0; k < 8; k++) acc[k] = fmaf(bf2f(xq[k]), w[k].z, acc[k]); }
    { ush8 xq = *(const ush8*)(base + (size_t)l * 768);
        #pragma unroll
        for (int k = 0; k < 8; k++) acc[k] = fmaf(bf2f(xq[k]), w[k].w, acc[k]); }
    ush8 o;
    #pragma unroll
    for (int k = 0; k < 8; k++) o[k] = f2bf(acc[k] * sigmoidf_(acc[k]));
    *(ush8*)(xcbf + (size_t)idx * 8) = o;
}

// ---------------- selective scan, v15: unrolled passes ----------------
// grid (64 b, 48 eg), block 512 = 8 waves; wave = one e (= eg*8+wave).
// n = lane&15 (D_STATE), c = lane>>4 (time chunk {52,48,48,48}).
// Both passes: peeled t=0..3 group (c==0 only) + 12 unrolled groups from
// the uniform base tb = 48c+4 -> ds_read base+immediate, no loop control.
__global__ __launch_bounds__(512, 6) void scan_kernel(const float* __restrict__ xdt,
        const ushort_t* __restrict__ xcbf, const ushort_t* __restrict__ xz,
        const float* __restrict__ dtw, const float* __restrict__ dtb,
        const float* __restrict__ a_log, const float* __restrict__ Dp, ushort_t* __restrict__ y) {
    __shared__ float sd[32 * 196];       // 25088 B  B rows 0..15, C rows 16..31
    __shared__ float dls[8][196];        // 6272 B   per-wave delta (f32)
    __shared__ float dus[8][196];        // 6272 B   per-wave delta*xc (f32)
    __shared__ ushort_t xcs[8 * 196];    // 3136 B   [e_off][l] bf16; y in-place
    // total 40,768 B
    const int b = blockIdx.x, eg = blockIdx.y;
    const int tid = threadIdx.x;
    const int wave = tid >> 6, lane = tid & 63;
    const int e = eg * 8 + wave;
    const int n = lane & 15, c = lane >> 4;

    {   // stage B/C rows (x_dbl rows 12..43) — contiguous float4 copy
        const float4* src4 = (const float4*)(xdt + (size_t)b * XDP + 12 * 196);
        float4* sd4 = (float4*)sd;
        for (int i = tid; i < 32 * 196 / 4; i += 512) sd4[i] = src4[i];
    }
    float wv = 0.f;
    if (lane < DR) wv = dtw[(size_t)e * DR + lane];  // pulled via readlane below
    float zb[8];                                      // z held in regs (f32)
    #pragma unroll
    for (int k = 0; k < 8; k++) zb[k] = 0.f;
    if (tid < 196) {  // stage xc (bf16) for the 8 e's; load z (bf16) into regs
        int l = tid;
        const ushort_t* xp = xcbf + (size_t)(b * SEQL + l) * DI + eg * 8;
        ushort4 xq0 = *(const ushort4*)xp;
        ushort4 xq1 = *(const ushort4*)(xp + 4);
        const ushort_t* zp = xz + (size_t)(b * SEQL + l) * 768 + DI + eg * 8;
        ushort4 zq0 = *(const ushort4*)zp;
        ushort4 zq1 = *(const ushort4*)(zp + 4);
        zb[0] = bf2f(zq0.x); zb[1] = bf2f(zq0.y); zb[2] = bf2f(zq0.z); zb[3] = bf2f(zq0.w);
        zb[4] = bf2f(zq1.x); zb[5] = bf2f(zq1.y); zb[6] = bf2f(zq1.z); zb[7] = bf2f(zq1.w);
        xcs[0 * 196 + l] = xq0.x; xcs[1 * 196 + l] = xq0.y;
        xcs[2 * 196 + l] = xq0.z; xcs[3 * 196 + l] = xq0.w;
        xcs[4 * 196 + l] = xq1.x; xcs[5 * 196 + l] = xq1.y;
        xcs[6 * 196 + l] = xq1.z; xcs[7 * 196 + l] = xq1.w;
    }
    __syncthreads();

    const float Avn = -__expf(a_log[(size_t)e * DS + n]) * LOG2E;  // per-lane scalar
    const float db = dtb[e];
    const bool act = lane < 49;
    const int lb = act ? lane * 4 : 0;

    // phase A: delta = softplus(dt . dt_w + db); du = delta*xc (49 lanes x 4 t).
    // dt rows read DIRECTLY from global (read-once; L2-hot from x_proj).
    if (act) {
        const float* dtg = xdt + (size_t)b * XDP;
        f32x4 dt4 = {db, db, db, db};
        #pragma unroll
        for (int k = 0; k < DR; k++) {
            f32x4 r = *(const f32x4*)&dtg[k * 196 + lb];
            dt4 += r * __shfl(wv, k);   // const k -> v_readlane (SGPR operand)
        }
        f32x4 d4;
        #pragma unroll
        for (int s = 0; s < 4; s++) {
            float v = dt4[s];
            d4[s] = (v > 20.f) ? v : __logf(1.f + __expf(v));
        }
        ushort4 xcq = *(const ushort4*)&xcs[wave * 196 + lb];
        f32x4 du4 = d4 * f32x4{bf2f(xcq.x), bf2f(xcq.y), bf2f(xcq.z), bf2f(xcq.w)};
        *(f32x4*)&dls[wave][lb] = d4;
        *(f32x4*)&dus[wave][lb] = du4;
    }
    // dls/dus are per-wave: same-wave ds_write -> ds_read is program-ordered.

    const int tb = 48 * c + 4;     // uniform unrolled base; chunk 0 peels t=0..3
    const float* dlw = dls[wave];
    const float* duw = dus[wave];
    const float* pdl = dlw + tb;
    const float* pdu = duw + tb;
    const float* pB  = &sd[n * 196] + tb;          // B rows at 0..15
    const float* pC  = &sd[(16 + n) * 196] + tb;   // C rows at 16..31

    // pass 1: local scan of own chunk (h from 0); P = exp2(Avn * sum(delta))
    float h = 0.f;
    f32x4 dsum = {0.f, 0.f, 0.f, 0.f};
    if (c == 0) {  // peeled group t=0..3
        f32x4 dl = *(const f32x4*)&dlw[0];
        f32x4 du = *(const f32x4*)&duw[0];
        f32x4 Bn = *(const f32x4*)&pB[-4];   // = &sd[n*196][0]
        dsum += dl;
        #pragma unroll
        for (int s = 0; s < 4; s++) {
            float dA = __builtin_amdgcn_exp2f(dl[s] * Avn);
            h = fmaf(h, dA, du[s] * Bn[s]);
        }
    }
    #pragma unroll
    for (int i = 0; i < 12; i++) {
        f32x4 dl = *(const f32x4*)&pdl[4 * i];
        f32x4 du = *(const f32x4*)&pdu[4 * i];
        f32x4 Bn = *(const f32x4*)&pB[4 * i];
        dsum += dl;
        #pragma unroll
        for (int s = 0; s < 4; s++) {
            float dA = __builtin_amdgcn_exp2f(dl[s] * Avn);
            h = fmaf(h, dA, du[s] * Bn[s]);
        }
    }
    float P = __builtin_amdgcn_exp2f(Avn * (dsum[0] + dsum[1] + dsum[2] + dsum[3]));

    // inclusive affine scan over the 4 chunks (lanes stride 16)
    {
        float hp = __shfl_up(h, 16), pp = __shfl_up(P, 16);
        if (c >= 1) { h = fmaf(P, hp, h); P *= pp; }
        hp = __shfl_up(h, 32); pp = __shfl_up(P, 32);
        if (c >= 2) { h = fmaf(P, hp, h); P *= pp; }
    }
    float hin = __shfl_up(h, 16);
    if (c == 0) hin = 0.f;

    // pass 2: replay with incoming state; y_t = sum_n h_n(t) C_n(t) + xc*D.
    // y (pre-gate) is written IN PLACE over xcs (xc consumed at same slot).
    const float Dv = Dp[e];
    ushort_t* xcw = &xcs[wave * 196];
    h = hin;
    if (c == 0) {  // peeled group t=0..3 (runs FIRST: sequential in t)
        f32x4 dl = *(const f32x4*)&dlw[0];
        f32x4 du = *(const f32x4*)&duw[0];
        f32x4 Bn = *(const f32x4*)&pB[-4];
        f32x4 Cn = *(const f32x4*)&pC[-4];
        f32x4 yp;
        #pragma unroll
        for (int s = 0; s < 4; s++) {
            float dA = __builtin_amdgcn_exp2f(dl[s] * Avn);
            h = fmaf(h, dA, du[s] * Bn[s]);
            yp[s] = h * Cn[s];
        }
        #pragma unroll
        for (int s = 0; s < 4; s++) yp[s] = row16_sum(yp[s]);
        if (n < 4) {
            float ysel = (n == 0) ? yp[0] : (n == 1) ? yp[1] : (n == 2) ? yp[2] : yp[3];
            float xcsel = bf2f(xcw[n]);
            xcw[n] = f2bf(fmaf(xcsel, Dv, ysel));
        }
    }
    #pragma unroll
    for (int i = 0; i < 12; i++) {
        int t = tb + 4 * i;
        f32x4 dl = *(const f32x4*)&pdl[4 * i];
        f32x4 du = *(const f32x4*)&pdu[4 * i];
        f32x4 Bn = *(const f32x4*)&pB[4 * i];
        f32x4 Cn = *(const f32x4*)&pC[4 * i];
        f32x4 yp;
        #pragma unroll
        for (int s = 0; s < 4; s++) {
            float dA = __builtin_amdgcn_exp2f(dl[s] * Avn);
            h = fmaf(h, dA, du[s] * Bn[s]);
            yp[s] = h * Cn[s];
        }
        #pragma unroll
        for (int s = 0; s < 4; s++) yp[s] = row16_sum(yp[s]);
        if (n < 4) {  // lane n finalizes timestep t+n
            float ysel = (n == 0) ? yp[0] : (n == 1) ? yp[1] : (n == 2) ? yp[2] : yp[3];
            float xcsel = bf2f(xcw[t + n]);
            xcw[t + n] = f2bf(fmaf(xcsel, Dv, ysel));
        }
    }
    __syncthreads();
    if (tid < 196) {  // cooperative gate + store of y for the 8 e's
        int l = tid;
        union { ushort_t s[8]; ushort4 q[2]; } o;
        #pragma unroll
        for (int k = 0; k < 8; k++) {
            float yv = bf2f(xcs[k * 196 + l]);
            float z = zb[k];
            o.s[k] = f2bf(yv * z * sigmoidf_(z));
        }
        ushort_t* yp = y + (size_t)(b * SEQL + l) * DI + eg * 8;
        *(ushort4*)yp = o.q[0];
        *(ushort4*)(yp + 4) = o.q[1];
    }
}

// ---------------- mean over L ----------------
__global__ void pool_kernel(const float* __restrict__ normed, float* __restrict__ pooled) {
    int b = blockIdx.x, d = threadIdx.x;
    float s = 0.f;
    for (int l = 0; l < SEQL; l++) s += normed[(size_t)(b * SEQL + l) * DM + d];
    pooled[b * DM + d] = s * (1.f / 196.f);
}

extern "C" void kernel_launch(void* const* d_in, const int* in_sizes, int n_in,
                              void* d_out, int out_size, void* d_ws, size_t ws_size,
                              hipStream_t stream) {
    const float* x       = (const float*)d_in[0];
    const float* patch_w = (const float*)d_in[1];
    const float* patch_b = (const float*)d_in[2];
    const float* norm_w  = (const float*)d_in[3];
    const float* norm_b  = (const float*)d_in[4];
    const float* in_w    = (const float*)d_in[5];
    const float* conv_w  = (const float*)d_in[6];
    const float* conv_b  = (const float*)d_in[7];
    const float* xp_w    = (const float*)d_in[8];
    const float* dt_w    = (const float*)d_in[9];
    const float* dt_b    = (const float*)d_in[10];
    const float* A_log   = (const float*)d_in[11];
    const float* Dp      = (const float*)d_in[12];
    const float* out_w   = (const float*)d_in[13];
    const float* normf_w = (const float*)d_in[14];
    const float* normf_b = (const float*)d_in[15];
    const float* head_w  = (const float*)d_in[16];
    const float* head_b  = (const float*)d_in[17];

    float* ws = (float*)d_ws;
    float* residual     = ws;                          // [0, 2408448)
    ushort_t* xz_bf     = (ushort_t*)(ws + 4816896);   // [4816896, 9633792) bf16 12544x768
    float* lnout        = ws + 9633792;                // [9633792, 12042240) final LN fp32
    ushort_t* xcbf      = (ushort_t*)(ws + 14450688);  // [14450688, 16859136)
    ushort_t* y_bf      = (ushort_t*)(ws + 16859136);  // [16859136, 19267584)
    ushort_t* x_bf      = (ushort_t*)(ws + 14450688);  // alias, dead before layer-0 conv
    ushort_t* normed_bf = (ushort_t*)(ws + 19267584);  // [19267584, 20471808)
    float* xdbl_t       = ws + 20471808;               // [20471808, 21023744)
    float* pooled       = ws + 21023744;               // [21023744, 21036032)
    ushort_t* in_w_bf   = (ushort_t*)(ws + 21036032);  // [21036032, 22805504)
    ushort_t* out_w_bf  = (ushort_t*)(ws + 22805504);  // [22805504, 23690240)
    ushort_t* xp_w_bf   = (ushort_t*)(ws + 23690240);  // [23690240, 23985152)
    ushort_t* patch_w_bf= (ushort_t*)(ws + 23985152);  // [23985152, 24058880)
    // end 24,058,880 floats = 96.2 MB

    f2bf4_kernel<<<3456, 256, 0, stream>>>(in_w, in_w_bf, 884736);
    f2bf4_kernel<<<1728, 256, 0, stream>>>(out_w, out_w_bf, 442368);
    f2bf4_kernel<<<144, 256, 0, stream>>>(patch_w, patch_w_bf, 36864);
    f2bf4_kernel<<<9408, 256, 0, stream>>>(x, x_bf, 2408448);
    xp_pad_kernel<<<2304, 256, 0, stream>>>(xp_w, xp_w_bf);

    // patch embed -> residual directly (replaces memset + first accumulation)
    gemm_patch_mfma<<<dim3(98, 3), 256, 0, stream>>>(x_bf, patch_w_bf, patch_b, residual);

    for (int d = 0; d < DEPTH; ++d) {
        ln_kernel<true><<<3136, 256, 0, stream>>>(residual, norm_w + d * DM,
                                                  norm_b + d * DM, normed_bf);
        // in_proj -> xz (bf16 output)
        gemm_mfma<128, 192, 2, 2, 12, false, false, true><<<dim3(98, 4), 256, 0, stream>>>(
                normed_bf, in_w_bf + (size_t)d * 768 * 192, xz_bf, 192, 768);
        conv_silu_kernel<<<2352, 256, 0, stream>>>(xz_bf, conv_w + d * DI * 4, conv_b + d * DI, xcbf);
        // x_proj -> transposed x_dbl [b][44][196]; BM=64 -> 196 blocks
        gemm_mfma<64, 64, 4, 1, 3, true, false, false><<<dim3(196, 1), 256, 0, stream>>>(xcbf,
                xp_w_bf + (size_t)d * 64 * 384, xdbl_t, 384, 196);
        scan_kernel<<<dim3(64, 48), 512, 0, stream>>>(xdbl_t, xcbf, xz_bf, dt_w + d * DI * DR,
                dt_b + d * DI, A_log + d * DI * DS, Dp + d * DI, y_bf);
        // out_proj with fused residual += ; BM=64 -> 588 blocks
        gemm_mfma<64, 64, 4, 1, 4, false, true, false><<<dim3(196, 3), 256, 0, stream>>>(y_bf,
                out_w_bf + (size_t)d * 192 * 384, residual, 384, 192);
    }

    ln_kernel<false><<<3136, 256, 0, stream>>>(residual, normf_w, normf_b, lnout);
    pool_kernel<<<64, 192, 0, stream>>>(lnout, pooled);
    gemm64<true><<<dim3(1, 16), 256, 0, stream>>>(pooled, head_w, head_b, (float*)d_out, 64, 1000, 192);
}

// Round 13
// 2873.703 us; speedup vs baseline: 1.0328x; 1.0328x over previous
//
#include <hip/hip_runtime.h>
#include <math.h>

// VisionMamba forward. Round 24: isolated revert — conv_silu back to the
// R22 4-e's/thread form (R23's 8-wide widening is the suspected ~116 µs
// regression: fewer blocks + 2x per-thread state on a latency-bound
// kernel). Scan stays v15 (unrolled, 65.5 µs — its VALU floor).
// B=64, L=196, D_MODEL=192, D_INNER=384, D_STATE=16, DT_RANK=12, DEPTH=24.

#define DEPTH 24
#define DM 192
#define DI 384
#define DS 16
#define DR 12
#define SEQL 196
#define BATCH 64
#define MROWS (BATCH*SEQL)   // 12544
#define XDP 8624             // x_dbl_t per-b plane: 44*196 floats
#define LOG2E 1.44269504088896340736f

typedef unsigned short ushort_t;
typedef __bf16 bf16x8 __attribute__((ext_vector_type(8)));
typedef float f32x4 __attribute__((ext_vector_type(4)));

__device__ __forceinline__ float sigmoidf_(float x) { return 1.f / (1.f + __expf(-x)); }

__device__ __forceinline__ ushort_t f2bf(float f) {  // RNE fp32->bf16
    union { float f; unsigned u; } c; c.f = f;
    unsigned u = c.u;
    return (ushort_t)((u + 0x7FFFu + ((u >> 16) & 1u)) >> 16);
}
__device__ __forceinline__ float bf2f(ushort_t u) {
    union { unsigned u; float f; } c; c.u = ((unsigned)u) << 16;
    return c.f;
}

__device__ __forceinline__ void load_lds16(const ushort_t* g, ushort_t* l) {
    __builtin_amdgcn_global_load_lds((__attribute__((address_space(1))) void*)g,
                                     (__attribute__((address_space(3))) void*)l, 16, 0, 0);
}

// DPP move: result = src permuted by CTRL; all perms used stay within valid
// lanes so `oldv` is never observed. Pure VALU, no LDS pipe.
template<int CTRL>
__device__ __forceinline__ float dpp_mov(float oldv, float src) {
    return __builtin_bit_cast(float, __builtin_amdgcn_update_dpp(
        __builtin_bit_cast(int, oldv), __builtin_bit_cast(int, src),
        CTRL, 0xF, 0xF, false));
}

// Butterfly sum over the 16 lanes of a DPP row: xor1, xor2, xor7, xor15
// generate the full 16-group; every lane ends with the row sum.
__device__ __forceinline__ float row16_sum(float v) {
    v += dpp_mov<0xB1>(0.f, v);   // quad_perm [1,0,3,2]  (xor 1)
    v += dpp_mov<0x4E>(0.f, v);   // quad_perm [2,3,0,1]  (xor 2)
    v += dpp_mov<0x141>(0.f, v);  // row_half_mirror      (xor 7)
    v += dpp_mov<0x140>(0.f, v);  // row_mirror           (xor 15)
    return v;
}

// ---------------- fp32 -> bf16 bulk convert, 4 elems/thread ----------------
__global__ void f2bf4_kernel(const float* __restrict__ src, ushort_t* __restrict__ dst, int n4) {
    int i = blockIdx.x * 256 + threadIdx.x;
    if (i >= n4) return;
    float4 v = ((const float4*)src)[i];
    union { ushort_t s[4]; uint2 u; } o;
    o.s[0] = f2bf(v.x); o.s[1] = f2bf(v.y); o.s[2] = f2bf(v.z); o.s[3] = f2bf(v.w);
    ((uint2*)dst)[i] = o.u;
}

// xp_w [24][44][384] -> padded bf16 [24][64][384], rows 44..63 = 0
__global__ void xp_pad_kernel(const float* __restrict__ src, ushort_t* __restrict__ dst) {
    int i = blockIdx.x * 256 + threadIdx.x;
    if (i >= DEPTH * 64 * 384) return;
    int col = i % 384, row = (i / 384) & 63, d = i / (384 * 64);
    float v = (row < 44) ? src[(size_t)d * 44 * 384 + row * 384 + col] : 0.f;
    dst[i] = f2bf(v);
}

// ---------------- out = LayerNorm(residual)  (no accumulation) ----------------
template<bool BF>
__global__ void ln_kernel(const float* __restrict__ residual,
                          const float* __restrict__ w, const float* __restrict__ b,
                          void* __restrict__ out_) {
    int wave = threadIdx.x >> 6, lane = threadIdx.x & 63;
    int row = blockIdx.x * 4 + wave;
    const float* rr = residual + (size_t)row * DM;
    float v0 = rr[lane];
    float v1 = rr[lane + 64];
    float v2 = rr[lane + 128];
    float s = v0 + v1 + v2;
    #pragma unroll
    for (int off = 32; off > 0; off >>= 1) s += __shfl_down(s, off);
    float mean = __shfl(s, 0) * (1.f / DM);
    float d0 = v0 - mean, d1 = v1 - mean, d2 = v2 - mean;
    float q = d0 * d0 + d1 * d1 + d2 * d2;
    #pragma unroll
    for (int off = 32; off > 0; off >>= 1) q += __shfl_down(q, off);
    float rstd = rsqrtf(__shfl(q, 0) * (1.f / DM) + 1e-5f);
    float o0 = d0 * rstd * w[lane]       + b[lane];
    float o1 = d1 * rstd * w[lane + 64]  + b[lane + 64];
    float o2 = d2 * rstd * w[lane + 128] + b[lane + 128];
    if constexpr (BF) {
        ushort_t* o = (ushort_t*)out_ + (size_t)row * DM;
        o[lane] = f2bf(o0); o[lane + 64] = f2bf(o1); o[lane + 128] = f2bf(o2);
    } else {
        float* o = (float*)out_ + (size_t)row * DM;
        o[lane] = o0; o[lane + 64] = o1; o[lane + 128] = o2;
    }
}

// ---------------- bf16 MFMA GEMM: C = A[M,K]bf16 * W[N,K]bf16^T ----------------
// BM parametrized. RESADD: C += result (fp32). OBF: write bf16 output.
template<int BM, int BN, int WM, int WN, int NST, bool TC, bool RESADD, bool OBF>
__global__ __launch_bounds__(256, 2) void gemm_mfma(const ushort_t* __restrict__ A,
        const ushort_t* __restrict__ W, void* __restrict__ C, int K, int ldC) {
    constexpr int FM = BM / (WM * 16);
    constexpr int FN = BN / (WN * 16);
    __shared__ ushort_t sA[BM * 32];
    __shared__ ushort_t sB[BN * 32];
    const int t = threadIdx.x;
    const int wave = t >> 6, lane = t & 63;
    const int lr = lane & 15, lq = lane >> 4;
    const int wr = wave / WN, wc = wave % WN;
    const int m0 = blockIdx.x * BM, n0 = blockIdx.y * BN;
    const int wbase = t & ~63;

    f32x4 acc[FM][FN];
    #pragma unroll
    for (int i = 0; i < FM; i++)
        #pragma unroll
        for (int j = 0; j < FN; j++) acc[i][j] = f32x4{0.f, 0.f, 0.f, 0.f};

    for (int k0 = 0; k0 < K; k0 += 32) {
        __syncthreads();
        #pragma unroll
        for (int c = 0; c < BM * 4 / 256; c++) { // A: BM*4 slots
            int s = c * 256 + t;
            int row = s >> 2;
            int quad = (s & 3) ^ ((row >> 1) & 3);
            load_lds16(A + (size_t)(m0 + row) * K + k0 + quad * 8,
                       sA + (size_t)(c * 256 + wbase) * 8);
        }
        #pragma unroll
        for (int c = 0; c < BN * 4 / 256; c++) { // B: BN*4 slots
            int s = c * 256 + t;
            int row = s >> 2;
            int quad = (s & 3) ^ ((row >> 1) & 3);
            load_lds16(W + (size_t)(n0 + row) * K + k0 + quad * 8,
                       sB + (size_t)(c * 256 + wbase) * 8);
        }
        __syncthreads();
        bf16x8 af[FM], bfr[FN];
        #pragma unroll
        for (int i = 0; i < FM; i++) {
            int row = wr * FM * 16 + i * 16 + lr;
            int slot = (row << 2) | (lq ^ ((row >> 1) & 3));
            af[i] = *(const bf16x8*)&sA[(size_t)slot * 8];
        }
        #pragma unroll
        for (int j = 0; j < FN; j++) {
            int row = wc * FN * 16 + j * 16 + lr;
            int slot = (row << 2) | (lq ^ ((row >> 1) & 3));
            bfr[j] = *(const bf16x8*)&sB[(size_t)slot * 8];
        }
        #pragma unroll
        for (int i = 0; i < FM; i++)
            #pragma unroll
            for (int j = 0; j < FN; j++)
                acc[i][j] = __builtin_amdgcn_mfma_f32_16x16x32_bf16(af[i], bfr[j], acc[i][j], 0, 0, 0);
    }
    // C/D layout: col = lane&15, row = (lane>>4)*4 + reg
    int crow0 = m0 + wr * FM * 16 + lq * 4;
    int ccol0 = n0 + wc * FN * 16 + lr;
    if constexpr (TC) {
        #pragma unroll
        for (int i = 0; i < FM; i++) {
            int m = crow0 + i * 16;
            int bb = m / 196, l = m % 196;
            #pragma unroll
            for (int j = 0; j < FN; j++) {
                int col = ccol0 + j * 16;
                if (col < 44) {
                    float4 v = {acc[i][j][0], acc[i][j][1], acc[i][j][2], acc[i][j][3]};
                    *(float4*)((float*)C + (size_t)bb * XDP + (size_t)col * 196 + l) = v;
                }
            }
        }
    } else {
        #pragma unroll
        for (int i = 0; i < FM; i++)
            #pragma unroll
            for (int j = 0; j < FN; j++) {
                if (wc * FN + j >= NST) continue;
                if constexpr (OBF) {
                    ushort_t* cp = (ushort_t*)C + (size_t)(crow0 + i * 16) * ldC + ccol0 + j * 16;
                    #pragma unroll
                    for (int r = 0; r < 4; r++) cp[(size_t)r * ldC] = f2bf(acc[i][j][r]);
                } else {
                    float* cp = (float*)C + (size_t)(crow0 + i * 16) * ldC + ccol0 + j * 16;
                    #pragma unroll
                    for (int r = 0; r < 4; r++) {
                        if constexpr (RESADD) cp[(size_t)r * ldC] += acc[i][j][r];
                        else                  cp[(size_t)r * ldC]  = acc[i][j][r];
                    }
                }
            }
    }
}

// ---------------- Patch-embed bf16 MFMA with im2col A-loader ----------------
// Writes the residual buffer directly (bias included) — replaces memset+add.
__global__ __launch_bounds__(256, 2) void gemm_patch_mfma(const ushort_t* __restrict__ Xbf,
        const ushort_t* __restrict__ Wbf, const float* __restrict__ bias, float* __restrict__ C) {
    constexpr int FM = 2, FN = 4;
    __shared__ ushort_t sA[128 * 32];
    __shared__ ushort_t sB[64 * 32];
    const int t = threadIdx.x;
    const int wave = t >> 6, lane = t & 63;
    const int lr = lane & 15, lq = lane >> 4;
    const int m0 = blockIdx.x * 128, n0 = blockIdx.y * 64;
    const int wbase = t & ~63;

    const ushort_t* abase[2];
    int aquad[2];
    #pragma unroll
    for (int c = 0; c < 2; c++) {
        int s = c * 256 + t;
        int row = s >> 2;
        aquad[c] = (s & 3) ^ ((row >> 1) & 3);
        int m = m0 + row;
        int b = m / 196, r = m % 196, py = r / 14, px = r % 14;
        abase[c] = Xbf + (size_t)b * 150528 + py * 3584 + px * 16;
    }
    int brow = t >> 2;
    int bquad = (t & 3) ^ ((brow >> 1) & 3);
    const ushort_t* bbase = Wbf + (size_t)(n0 + brow) * 768 + bquad * 8;

    f32x4 acc[FM][FN];
    #pragma unroll
    for (int i = 0; i < FM; i++)
        #pragma unroll
        for (int j = 0; j < FN; j++) acc[i][j] = f32x4{0.f, 0.f, 0.f, 0.f};

    for (int k0 = 0; k0 < 768; k0 += 32) {
        __syncthreads();
        #pragma unroll
        for (int c = 0; c < 2; c++) {
            int k = k0 + aquad[c] * 8;
            int ci = k >> 8, ky = (k >> 4) & 15, kx0 = k & 15;
            load_lds16(abase[c] + ci * 50176 + ky * 224 + kx0,
                       sA + (size_t)(c * 256 + wbase) * 8);
        }
        load_lds16(bbase + k0, sB + (size_t)wbase * 8);
        __syncthreads();
        bf16x8 af[FM], bfr[FN];
        #pragma unroll
        for (int i = 0; i < FM; i++) {
            int row = wave * FM * 16 + i * 16 + lr;
            int slot = (row << 2) | (lq ^ ((row >> 1) & 3));
            af[i] = *(const bf16x8*)&sA[(size_t)slot * 8];
        }
        #pragma unroll
        for (int j = 0; j < FN; j++) {
            int row = j * 16 + lr;
            int slot = (row << 2) | (lq ^ ((row >> 1) & 3));
            bfr[j] = *(const bf16x8*)&sB[(size_t)slot * 8];
        }
        #pragma unroll
        for (int i = 0; i < FM; i++)
            #pragma unroll
            for (int j = 0; j < FN; j++)
                acc[i][j] = __builtin_amdgcn_mfma_f32_16x16x32_bf16(af[i], bfr[j], acc[i][j], 0, 0, 0);
    }
    int crow0 = m0 + wave * FM * 16 + lq * 4;
    int ccol0 = n0 + lr;
    #pragma unroll
    for (int i = 0; i < FM; i++)
        #pragma unroll
        for (int j = 0; j < FN; j++) {
            int col = ccol0 + j * 16;
            float bv = bias[col];
            float* cp = C + (size_t)(crow0 + i * 16) * DM + col;
            #pragma unroll
            for (int r = 0; r < 4; r++) cp[(size_t)r * DM] = acc[i][j][r] + bv;
        }
}

// ---------------- Small fp32 GEMM (head only) ----------------
template<bool BIAS>
__global__ __launch_bounds__(256, 2) void gemm64(const float* __restrict__ A,
        const float* __restrict__ W, const float* __restrict__ bias,
        float* __restrict__ C, int M, int N, int K) {
    __shared__ float As[32][68];
    __shared__ float Ws[32][68];
    int t = threadIdx.x;
    int m0 = blockIdx.x * 64, n0 = blockIdx.y * 64;
    int lr = t >> 2, lk = (t & 3) * 4;
    int am = m0 + lr; bool avld = am < M;
    const float* Ap = A + (size_t)(avld ? am : 0) * K + lk;
    int wn = n0 + lr; bool wv = wn < N;
    const float* Wp = W + (size_t)(wv ? wn : 0) * K + lk;
    int tm = (t >> 4) * 4, tn = (t & 15) * 4;
    float acc[4][4];
    #pragma unroll
    for (int i = 0; i < 4; i++)
        #pragma unroll
        for (int j = 0; j < 4; j++) acc[i][j] = 0.f;

    for (int k0 = 0; k0 < K; k0 += 32) {
        float4 a0 = make_float4(0.f, 0.f, 0.f, 0.f), a1 = a0, w0 = a0, w1 = a0;
        if (avld) { a0 = *(const float4*)(Ap + k0); a1 = *(const float4*)(Ap + k0 + 16); }
        if (wv)   { w0 = *(const float4*)(Wp + k0); w1 = *(const float4*)(Wp + k0 + 16); }
        __syncthreads();
        As[lk + 0][lr] = a0.x; As[lk + 1][lr] = a0.y; As[lk + 2][lr] = a0.z; As[lk + 3][lr] = a0.w;
        As[lk + 16][lr] = a1.x; As[lk + 17][lr] = a1.y; As[lk + 18][lr] = a1.z; As[lk + 19][lr] = a1.w;
        Ws[lk + 0][lr] = w0.x; Ws[lk + 1][lr] = w0.y; Ws[lk + 2][lr] = w0.z; Ws[lk + 3][lr] = w0.w;
        Ws[lk + 16][lr] = w1.x; Ws[lk + 17][lr] = w1.y; Ws[lk + 18][lr] = w1.z; Ws[lk + 19][lr] = w1.w;
        __syncthreads();
        #pragma unroll
        for (int kk = 0; kk < 32; kk++) {
            float4 x0 = *(const float4*)&As[kk][tm];
            float4 y0 = *(const float4*)&Ws[kk][tn];
            float av[4] = {x0.x, x0.y, x0.z, x0.w};
            float bv[4] = {y0.x, y0.y, y0.z, y0.w};
            #pragma unroll
            for (int i = 0; i < 4; i++)
                #pragma unroll
                for (int j = 0; j < 4; j++) acc[i][j] = fmaf(av[i], bv[j], acc[i][j]);
        }
    }
    #pragma unroll
    for (int i = 0; i < 4; i++) {
        int m = m0 + tm + i;
        if (m >= M) continue;
        float* cr = C + (size_t)m * N;
        int n = n0 + tn;
        if (n < N) {
            float4 v = {acc[i][0], acc[i][1], acc[i][2], acc[i][3]};
            if (BIAS) { v.x += bias[n]; v.y += bias[n + 1]; v.z += bias[n + 2]; v.w += bias[n + 3]; }
            *(float4*)(cr + n) = v;
        }
    }
}

// ------------- depthwise causal conv(4) + SiLU (bf16 in) -> bf16, 4 e's/thread ----
__global__ void conv_silu_kernel(const ushort_t* __restrict__ xz, const float* __restrict__ cw,
                                 const float* __restrict__ cb, ushort_t* __restrict__ xcbf) {
    int idx = blockIdx.x * 256 + threadIdx.x;
    if (idx >= MROWS * (DI / 4)) return;
    int eq = idx % (DI / 4); int bl = idx / (DI / 4);
    int l = bl % SEQL; int b = bl / SEQL;
    int e4 = eq * 4;
    const ushort_t* base = xz + (size_t)(b * SEQL) * 768 + e4;
    float4 wa = *(const float4*)(cw + (e4 + 0) * 4);   // taps of e4+0
    float4 wb = *(const float4*)(cw + (e4 + 1) * 4);
    float4 wc = *(const float4*)(cw + (e4 + 2) * 4);
    float4 wd = *(const float4*)(cw + (e4 + 3) * 4);
    float4 acc = *(const float4*)(cb + e4);
    if (l >= 3) { ushort4 xq = *(const ushort4*)(base + (size_t)(l - 3) * 768);
        acc.x = fmaf(bf2f(xq.x), wa.x, acc.x); acc.y = fmaf(bf2f(xq.y), wb.x, acc.y);
        acc.z = fmaf(bf2f(xq.z), wc.x, acc.z); acc.w = fmaf(bf2f(xq.w), wd.x, acc.w); }
    if (l >= 2) { ushort4 xq = *(const ushort4*)(base + (size_t)(l - 2) * 768);
        acc.x = fmaf(bf2f(xq.x), wa.y, acc.x); acc.y = fmaf(bf2f(xq.y), wb.y, acc.y);
        acc.z = fmaf(bf2f(xq.z), wc.y, acc.z); acc.w = fmaf(bf2f(xq.w), wd.y, acc.w); }
    if (l >= 1) { ushort4 xq = *(const ushort4*)(base + (size_t)(l - 1) * 768);
        acc.x = fmaf(bf2f(xq.x), wa.z, acc.x); acc.y = fmaf(bf2f(xq.y), wb.z, acc.y);
        acc.z = fmaf(bf2f(xq.z), wc.z, acc.z); acc.w = fmaf(bf2f(xq.w), wd.z, acc.w); }
    { ushort4 xq = *(const ushort4*)(base + (size_t)l * 768);
        acc.x = fmaf(bf2f(xq.x), wa.w, acc.x); acc.y = fmaf(bf2f(xq.y), wb.w, acc.y);
        acc.z = fmaf(bf2f(xq.z), wc.w, acc.z); acc.w = fmaf(bf2f(xq.w), wd.w, acc.w); }
    ushort4 o;
    o.x = f2bf(acc.x * sigmoidf_(acc.x));
    o.y = f2bf(acc.y * sigmoidf_(acc.y));
    o.z = f2bf(acc.z * sigmoidf_(acc.z));
    o.w = f2bf(acc.w * sigmoidf_(acc.w));
    *(ushort4*)(xcbf + (size_t)idx * 4) = o;
}

// ---------------- selective scan, v15: unrolled passes ----------------
// grid (64 b, 48 eg), block 512 = 8 waves; wave = one e (= eg*8+wave).
// n = lane&15 (D_STATE), c = lane>>4 (time chunk {52,48,48,48}).
// Both passes: peeled t=0..3 group (c==0 only) + 12 unrolled groups from
// the uniform base tb = 48c+4 -> ds_read base+immediate, no loop control.
__global__ __launch_bounds__(512, 6) void scan_kernel(const float* __restrict__ xdt,
        const ushort_t* __restrict__ xcbf, const ushort_t* __restrict__ xz,
        const float* __restrict__ dtw, const float* __restrict__ dtb,
        const float* __restrict__ a_log, const float* __restrict__ Dp, ushort_t* __restrict__ y) {
    __shared__ float sd[32 * 196];       // 25088 B  B rows 0..15, C rows 16..31
    __shared__ float dls[8][196];        // 6272 B   per-wave delta (f32)
    __shared__ float dus[8][196];        // 6272 B   per-wave delta*xc (f32)
    __shared__ ushort_t xcs[8 * 196];    // 3136 B   [e_off][l] bf16; y in-place
    // total 40,768 B
    const int b = blockIdx.x, eg = blockIdx.y;
    const int tid = threadIdx.x;
    const int wave = tid >> 6, lane = tid & 63;
    const int e = eg * 8 + wave;
    const int n = lane & 15, c = lane >> 4;

    {   // stage B/C rows (x_dbl rows 12..43) — contiguous float4 copy
        const float4* src4 = (const float4*)(xdt + (size_t)b * XDP + 12 * 196);
        float4* sd4 = (float4*)sd;
        for (int i = tid; i < 32 * 196 / 4; i += 512) sd4[i] = src4[i];
    }
    float wv = 0.f;
    if (lane < DR) wv = dtw[(size_t)e * DR + lane];  // pulled via readlane below
    float zb[8];                                      // z held in regs (f32)
    #pragma unroll
    for (int k = 0; k < 8; k++) zb[k] = 0.f;
    if (tid < 196) {  // stage xc (bf16) for the 8 e's; load z (bf16) into regs
        int l = tid;
        const ushort_t* xp = xcbf + (size_t)(b * SEQL + l) * DI + eg * 8;
        ushort4 xq0 = *(const ushort4*)xp;
        ushort4 xq1 = *(const ushort4*)(xp + 4);
        const ushort_t* zp = xz + (size_t)(b * SEQL + l) * 768 + DI + eg * 8;
        ushort4 zq0 = *(const ushort4*)zp;
        ushort4 zq1 = *(const ushort4*)(zp + 4);
        zb[0] = bf2f(zq0.x); zb[1] = bf2f(zq0.y); zb[2] = bf2f(zq0.z); zb[3] = bf2f(zq0.w);
        zb[4] = bf2f(zq1.x); zb[5] = bf2f(zq1.y); zb[6] = bf2f(zq1.z); zb[7] = bf2f(zq1.w);
        xcs[0 * 196 + l] = xq0.x; xcs[1 * 196 + l] = xq0.y;
        xcs[2 * 196 + l] = xq0.z; xcs[3 * 196 + l] = xq0.w;
        xcs[4 * 196 + l] = xq1.x; xcs[5 * 196 + l] = xq1.y;
        xcs[6 * 196 + l] = xq1.z; xcs[7 * 196 + l] = xq1.w;
    }
    __syncthreads();

    const float Avn = -__expf(a_log[(size_t)e * DS + n]) * LOG2E;  // per-lane scalar
    const float db = dtb[e];
    const bool act = lane < 49;
    const int lb = act ? lane * 4 : 0;

    // phase A: delta = softplus(dt . dt_w + db); du = delta*xc (49 lanes x 4 t).
    // dt rows read DIRECTLY from global (read-once; L2-hot from x_proj).
    if (act) {
        const float* dtg = xdt + (size_t)b * XDP;
        f32x4 dt4 = {db, db, db, db};
        #pragma unroll
        for (int k = 0; k < DR; k++) {
            f32x4 r = *(const f32x4*)&dtg[k * 196 + lb];
            dt4 += r * __shfl(wv, k);   // const k -> v_readlane (SGPR operand)
        }
        f32x4 d4;
        #pragma unroll
        for (int s = 0; s < 4; s++) {
            float v = dt4[s];
            d4[s] = (v > 20.f) ? v : __logf(1.f + __expf(v));
        }
        ushort4 xcq = *(const ushort4*)&xcs[wave * 196 + lb];
        f32x4 du4 = d4 * f32x4{bf2f(xcq.x), bf2f(xcq.y), bf2f(xcq.z), bf2f(xcq.w)};
        *(f32x4*)&dls[wave][lb] = d4;
        *(f32x4*)&dus[wave][lb] = du4;
    }
    // dls/dus are per-wave: same-wave ds_write -> ds_read is program-ordered.

    const int tb = 48 * c + 4;     // uniform unrolled base; chunk 0 peels t=0..3
    const float* dlw = dls[wave];
    const float* duw = dus[wave];
    const float* pdl = dlw + tb;
    const float* pdu = duw + tb;
    const float* pB  = &sd[n * 196] + tb;          // B rows at 0..15
    const float* pC  = &sd[(16 + n) * 196] + tb;   // C rows at 16..31

    // pass 1: local scan of own chunk (h from 0); P = exp2(Avn * sum(delta))
    float h = 0.f;
    f32x4 dsum = {0.f, 0.f, 0.f, 0.f};
    if (c == 0) {  // peeled group t=0..3
        f32x4 dl = *(const f32x4*)&dlw[0];
        f32x4 du = *(const f32x4*)&duw[0];
        f32x4 Bn = *(const f32x4*)&pB[-4];   // = &sd[n*196][0]
        dsum += dl;
        #pragma unroll
        for (int s = 0; s < 4; s++) {
            float dA = __builtin_amdgcn_exp2f(dl[s] * Avn);
            h = fmaf(h, dA, du[s] * Bn[s]);
        }
    }
    #pragma unroll
    for (int i = 0; i < 12; i++) {
        f32x4 dl = *(const f32x4*)&pdl[4 * i];
        f32x4 du = *(const f32x4*)&pdu[4 * i];
        f32x4 Bn = *(const f32x4*)&pB[4 * i];
        dsum += dl;
        #pragma unroll
        for (int s = 0; s < 4; s++) {
            float dA = __builtin_amdgcn_exp2f(dl[s] * Avn);
            h = fmaf(h, dA, du[s] * Bn[s]);
        }
    }
    float P = __builtin_amdgcn_exp2f(Avn * (dsum[0] + dsum[1] + dsum[2] + dsum[3]));

    // inclusive affine scan over the 4 chunks (lanes stride 16)
    {
        float hp = __shfl_up(h, 16), pp = __shfl_up(P, 16);
        if (c >= 1) { h = fmaf(P, hp, h); P *= pp; }
        hp = __shfl_up(h, 32); pp = __shfl_up(P, 32);
        if (c >= 2) { h = fmaf(P, hp, h); P *= pp; }
    }
    float hin = __shfl_up(h, 16);
    if (c == 0) hin = 0.f;

    // pass 2: replay with incoming state; y_t = sum_n h_n(t) C_n(t) + xc*D.
    // y (pre-gate) is written IN PLACE over xcs (xc consumed at same slot).
    const float Dv = Dp[e];
    ushort_t* xcw = &xcs[wave * 196];
    h = hin;
    if (c == 0) {  // peeled group t=0..3 (runs FIRST: sequential in t)
        f32x4 dl = *(const f32x4*)&dlw[0];
        f32x4 du = *(const f32x4*)&duw[0];
        f32x4 Bn = *(const f32x4*)&pB[-4];
        f32x4 Cn = *(const f32x4*)&pC[-4];
        f32x4 yp;
        #pragma unroll
        for (int s = 0; s < 4; s++) {
            float dA = __builtin_amdgcn_exp2f(dl[s] * Avn);
            h = fmaf(h, dA, du[s] * Bn[s]);
            yp[s] = h * Cn[s];
        }
        #pragma unroll
        for (int s = 0; s < 4; s++) yp[s] = row16_sum(yp[s]);
        if (n < 4) {
            float ysel = (n == 0) ? yp[0] : (n == 1) ? yp[1] : (n == 2) ? yp[2] : yp[3];
            float xcsel = bf2f(xcw[n]);
            xcw[n] = f2bf(fmaf(xcsel, Dv, ysel));
        }
    }
    #pragma unroll
    for (int i = 0; i < 12; i++) {
        int t = tb + 4 * i;
        f32x4 dl = *(const f32x4*)&pdl[4 * i];
        f32x4 du = *(const f32x4*)&pdu[4 * i];
        f32x4 Bn = *(const f32x4*)&pB[4 * i];
        f32x4 Cn = *(const f32x4*)&pC[4 * i];
        f32x4 yp;
        #pragma unroll
        for (int s = 0; s < 4; s++) {
            float dA = __builtin_amdgcn_exp2f(dl[s] * Avn);
            h = fmaf(h, dA, du[s] * Bn[s]);
            yp[s] = h * Cn[s];
        }
        #pragma unroll
        for (int s = 0; s < 4; s++) yp[s] = row16_sum(yp[s]);
        if (n < 4) {  // lane n finalizes timestep t+n
            float ysel = (n == 0) ? yp[0] : (n == 1) ? yp[1] : (n == 2) ? yp[2] : yp[3];
            float xcsel = bf2f(xcw[t + n]);
            xcw[t + n] = f2bf(fmaf(xcsel, Dv, ysel));
        }
    }
    __syncthreads();
    if (tid < 196) {  // cooperative gate + store of y for the 8 e's
        int l = tid;
        union { ushort_t s[8]; ushort4 q[2]; } o;
        #pragma unroll
        for (int k = 0; k < 8; k++) {
            float yv = bf2f(xcs[k * 196 + l]);
            float z = zb[k];
            o.s[k] = f2bf(yv * z * sigmoidf_(z));
        }
        ushort_t* yp = y + (size_t)(b * SEQL + l) * DI + eg * 8;
        *(ushort4*)yp = o.q[0];
        *(ushort4*)(yp + 4) = o.q[1];
    }
}

// ---------------- mean over L ----------------
__global__ void pool_kernel(const float* __restrict__ normed, float* __restrict__ pooled) {
    int b = blockIdx.x, d = threadIdx.x;
    float s = 0.f;
    for (int l = 0; l < SEQL; l++) s += normed[(size_t)(b * SEQL + l) * DM + d];
    pooled[b * DM + d] = s * (1.f / 196.f);
}

extern "C" void kernel_launch(void* const* d_in, const int* in_sizes, int n_in,
                              void* d_out, int out_size, void* d_ws, size_t ws_size,
                              hipStream_t stream) {
    const float* x       = (const float*)d_in[0];
    const float* patch_w = (const float*)d_in[1];
    const float* patch_b = (const float*)d_in[2];
    const float* norm_w  = (const float*)d_in[3];
    const float* norm_b  = (const float*)d_in[4];
    const float* in_w    = (const float*)d_in[5];
    const float* conv_w  = (const float*)d_in[6];
    const float* conv_b  = (const float*)d_in[7];
    const float* xp_w    = (const float*)d_in[8];
    const float* dt_w    = (const float*)d_in[9];
    const float* dt_b    = (const float*)d_in[10];
    const float* A_log   = (const float*)d_in[11];
    const float* Dp      = (const float*)d_in[12];
    const float* out_w   = (const float*)d_in[13];
    const float* normf_w = (const float*)d_in[14];
    const float* normf_b = (const float*)d_in[15];
    const float* head_w  = (const float*)d_in[16];
    const float* head_b  = (const float*)d_in[17];

    float* ws = (float*)d_ws;
    float* residual     = ws;                          // [0, 2408448)
    ushort_t* xz_bf     = (ushort_t*)(ws + 4816896);   // [4816896, 9633792) bf16 12544x768
    float* lnout        = ws + 9633792;                // [9633792, 12042240) final LN fp32
    ushort_t* xcbf      = (ushort_t*)(ws + 14450688);  // [14450688, 16859136)
    ushort_t* y_bf      = (ushort_t*)(ws + 16859136);  // [16859136, 19267584)
    ushort_t* x_bf      = (ushort_t*)(ws + 14450688);  // alias, dead before layer-0 conv
    ushort_t* normed_bf = (ushort_t*)(ws + 19267584);  // [19267584, 20471808)
    float* xdbl_t       = ws + 20471808;               // [20471808, 21023744)
    float* pooled       = ws + 21023744;               // [21023744, 21036032)
    ushort_t* in_w_bf   = (ushort_t*)(ws + 21036032);  // [21036032, 22805504)
    ushort_t* out_w_bf  = (ushort_t*)(ws + 22805504);  // [22805504, 23690240)
    ushort_t* xp_w_bf   = (ushort_t*)(ws + 23690240);  // [23690240, 23985152)
    ushort_t* patch_w_bf= (ushort_t*)(ws + 23985152);  // [23985152, 24058880)
    // end 24,058,880 floats = 96.2 MB

    f2bf4_kernel<<<3456, 256, 0, stream>>>(in_w, in_w_bf, 884736);
    f2bf4_kernel<<<1728, 256, 0, stream>>>(out_w, out_w_bf, 442368);
    f2bf4_kernel<<<144, 256, 0, stream>>>(patch_w, patch_w_bf, 36864);
    f2bf4_kernel<<<9408, 256, 0, stream>>>(x, x_bf, 2408448);
    xp_pad_kernel<<<2304, 256, 0, stream>>>(xp_w, xp_w_bf);

    // patch embed -> residual directly (replaces memset + first accumulation)
    gemm_patch_mfma<<<dim3(98, 3), 256, 0, stream>>>(x_bf, patch_w_bf, patch_b, residual);

    for (int d = 0; d < DEPTH; ++d) {
        ln_kernel<true><<<3136, 256, 0, stream>>>(residual, norm_w + d * DM,
                                                  norm_b + d * DM, normed_bf);
        // in_proj -> xz (bf16 output)
        gemm_mfma<128, 192, 2, 2, 12, false, false, true><<<dim3(98, 4), 256, 0, stream>>>(
                normed_bf, in_w_bf + (size_t)d * 768 * 192, xz_bf, 192, 768);
        conv_silu_kernel<<<4704, 256, 0, stream>>>(xz_bf, conv_w + d * DI * 4, conv_b + d * DI, xcbf);
        // x_proj -> transposed x_dbl [b][44][196]; BM=64 -> 196 blocks
        gemm_mfma<64, 64, 4, 1, 3, true, false, false><<<dim3(196, 1), 256, 0, stream>>>(xcbf,
                xp_w_bf + (size_t)d * 64 * 384, xdbl_t, 384, 196);
        scan_kernel<<<dim3(64, 48), 512, 0, stream>>>(xdbl_t, xcbf, xz_bf, dt_w + d * DI * DR,
                dt_b + d * DI, A_log + d * DI * DS, Dp + d * DI, y_bf);
        // out_proj with fused residual += ; BM=64 -> 588 blocks
        gemm_mfma<64, 64, 4, 1, 4, false, true, false><<<dim3(196, 3), 256, 0, stream>>>(y_bf,
                out_w_bf + (size_t)d * 192 * 384, residual, 384, 192);
    }

    ln_kernel<false><<<3136, 256, 0, stream>>>(residual, normf_w, normf_b, lnout);
    pool_kernel<<<64, 192, 0, stream>>>(lnout, pooled);
    gemm64<true><<<dim3(1, 16), 256, 0, stream>>>(pooled, head_w, head_b, (float*)d_out, 64, 1000, 192);
}